// Round 2
// baseline (2955.574 us; speedup 1.0000x reference)
//
#include <hip/hip_runtime.h>
#include <hip/hip_bf16.h>

// RGCN on MI355X — round 2: workspace-safe fp32 baseline (bf16 h only).
//
// Round-1 post-mortem: first launch passed (absmax 0.0078) but post-timing
// output diverged persistently -> pristine input copies were corrupted.
// Cause: used ~107MB of d_ws without checking ws_size (OOB write past d_ws).
// Fix: feature-chunked pipeline, h in bf16, layer-1 accumulator aliased into
// d_out. Peak ws = 53.6MB (FC=64) or 40.8MB (FC=32), picked from ws_size.

constexpr int TPB = 256;

__global__ void count_kernel(const int* __restrict__ edges, unsigned* __restrict__ cnt,
                             int total, int E, int N) {
    int i = blockIdx.x * blockDim.x + threadIdx.x;
    if (i >= total) return;
    int node = edges[i];
    int slot = i / E;  // (r*2+side) per flat layout [3][2][E]
    atomicAdd(&cnt[slot * N + node], 1u);
}

// s[i] = rsqrt(max(cnt[i],1)), written in place over the count buffer.
__global__ void scale_inplace_kernel(unsigned* __restrict__ buf, int total) {
    int i = blockIdx.x * blockDim.x + threadIdx.x;
    if (i >= total) return;
    unsigned c = buf[i];
    ((float*)buf)[i] = rsqrtf((float)(c ? c : 1u));
}

// acc[n*FC + j] = sum_r b[r*FT + c0 + j]   (acc compact [N,FC])
template <int FC>
__global__ void init_bias_kernel(const float* __restrict__ b, int FT, int c0,
                                 float* __restrict__ acc, int N) {
    int i = blockIdx.x * blockDim.x + threadIdx.x;
    if (i >= N * FC) return;
    int j = i & (FC - 1);
    acc[i] = b[c0 + j] + b[FT + c0 + j] + b[2 * FT + c0 + j];
}

__device__ __forceinline__ float to_f(float v) { return v; }
__device__ __forceinline__ float to_f(__hip_bfloat16 v) { return __bfloat162float(v); }

// T[N,FC] = X[N,128] @ W[128, c0:c0+FC]  (W row stride WS). fp32 LDS-tiled.
// BM=64 rows/block, 256 threads as 16x16, each thread 4 rows x FC/16 cols.
template <int FC, typename XT>
__global__ __launch_bounds__(256) void gemm_kernel(const XT* __restrict__ X,
                                                   const float* __restrict__ W, int WS, int c0,
                                                   float* __restrict__ T, int N) {
    constexpr int BM = 64, KC = 32, K = 128, TN = FC / 16;
    __shared__ float Xs[BM][KC + 1];
    __shared__ float Bs[KC][FC];

    const int m0 = blockIdx.x * BM;
    const int t  = threadIdx.x;
    const int tr = t >> 4;
    const int tc = t & 15;

    float acc[4][TN];
#pragma unroll
    for (int i = 0; i < 4; ++i)
#pragma unroll
        for (int j = 0; j < TN; ++j) acc[i][j] = 0.f;

    for (int kc = 0; kc < K; kc += KC) {
        for (int i = t; i < BM * KC; i += 256) {
            int r = i >> 5, k = i & 31;
            int row = m0 + r;
            Xs[r][k] = (row < N) ? to_f(X[row * K + kc + k]) : 0.f;
        }
        for (int i = t; i < KC * FC; i += 256) {
            int kk = i / FC, c = i % FC;
            Bs[kk][c] = W[(kc + kk) * WS + c0 + c];
        }
        __syncthreads();
#pragma unroll
        for (int k = 0; k < KC; ++k) {
            float a[4], bb[TN];
#pragma unroll
            for (int i = 0; i < 4; ++i) a[i] = Xs[tr * 4 + i][k];
#pragma unroll
            for (int j = 0; j < TN; ++j) bb[j] = Bs[k][tc * TN + j];
#pragma unroll
            for (int i = 0; i < 4; ++i)
#pragma unroll
                for (int j = 0; j < TN; ++j) acc[i][j] += a[i] * bb[j];
        }
        __syncthreads();
    }

#pragma unroll
    for (int i = 0; i < 4; ++i) {
        int row = m0 + tr * 4 + i;
        if (row < N) {
#pragma unroll
            for (int j = 0; j < TN; ++j) T[row * FC + tc * TN + j] = acc[i][j];
        }
    }
}

// acc[dst*accStride + j] += T[src*FC + j] * s_out[src] * s_in[dst]
template <int FC>
__global__ void scatter_kernel(const int* __restrict__ src, const int* __restrict__ dst,
                               const float* __restrict__ T,
                               const float* __restrict__ s_out, const float* __restrict__ s_in,
                               float* __restrict__ acc, int accStride, int E) {
    constexpr int LPE = FC / 4;
    int gid = blockIdx.x * blockDim.x + threadIdx.x;
    int e = gid / LPE;
    if (e >= E) return;
    int j = (gid % LPE) * 4;
    int sN = src[e], dN = dst[e];
    float w = s_out[sN] * s_in[dN];
    float4 v = *reinterpret_cast<const float4*>(&T[sN * FC + j]);
    float* p = &acc[dN * accStride + j];
    atomicAdd(p + 0, v.x * w);
    atomicAdd(p + 1, v.y * w);
    atomicAdd(p + 2, v.z * w);
    atomicAdd(p + 3, v.w * w);
}

// h[n*128 + c0 + j] = bf16(relu(acc[n*FC + j]))
template <int FC>
__global__ void relu_store_h_kernel(const float* __restrict__ acc, __hip_bfloat16* __restrict__ h,
                                    int c0, int N) {
    int i = blockIdx.x * blockDim.x + threadIdx.x;
    if (i >= N * FC) return;
    int n = i / FC, j = i & (FC - 1);
    h[n * 128 + c0 + j] = __float2bfloat16(fmaxf(acc[i], 0.f));
}

__global__ void relu_kernel(float* __restrict__ a, int total) {
    int i = blockIdx.x * blockDim.x + threadIdx.x;
    if (i >= total) return;
    a[i] = fmaxf(a[i], 0.f);
}

static inline int cdiv(int a, int b) { return (a + b - 1) / b; }

template <int FC>
static void run_pipeline(const float* x, const float* W1, const float* b1,
                         const float* W2, const float* b2, const int* edges,
                         float* out, void* d_ws, int N, int E, hipStream_t stream) {
    // ws layout: [ s: 6N f32 (counts in place) | h: N*128 bf16 | tmp: N*FC f32 ]
    char* w = (char*)d_ws;
    unsigned* cnt = (unsigned*)w;          // aliased with s
    float* s = (float*)w;                  w += (size_t)6 * N * sizeof(float);
    __hip_bfloat16* h = (__hip_bfloat16*)w; w += (size_t)N * 128 * sizeof(__hip_bfloat16);
    float* tmp = (float*)w;

    hipMemsetAsync(cnt, 0, (size_t)6 * N * sizeof(unsigned), stream);
    count_kernel<<<cdiv(6 * E, TPB), TPB, 0, stream>>>(edges, cnt, 6 * E, E, N);
    scale_inplace_kernel<<<cdiv(6 * N, TPB), TPB, 0, stream>>>(cnt, 6 * N);

    // ---- layer 1: 128 -> 128, acc aliased into d_out (N*FC f32 <= N*64 f32) ----
    for (int c0 = 0; c0 < 128; c0 += FC) {
        init_bias_kernel<FC><<<cdiv(N * FC, TPB), TPB, 0, stream>>>(b1, 128, c0, out, N);
        for (int r = 0; r < 3; ++r) {
            gemm_kernel<FC, float><<<cdiv(N, 64), 256, 0, stream>>>(
                x, W1 + (size_t)r * 128 * 128, 128, c0, tmp, N);
            scatter_kernel<FC><<<cdiv(E * (FC / 4), TPB), TPB, 0, stream>>>(
                edges + (size_t)(r * 2 + 0) * E, edges + (size_t)(r * 2 + 1) * E,
                tmp, s + (size_t)(r * 2 + 0) * N, s + (size_t)(r * 2 + 1) * N, out, FC, E);
        }
        relu_store_h_kernel<FC><<<cdiv(N * FC, TPB), TPB, 0, stream>>>(out, h, c0, N);
    }

    // ---- layer 2: 128 -> 64, accumulate directly into d_out ----
    init_bias_kernel<64><<<cdiv(N * 64, TPB), TPB, 0, stream>>>(b2, 64, 0, out, N);
    for (int c0 = 0; c0 < 64; c0 += FC) {
        for (int r = 0; r < 3; ++r) {
            gemm_kernel<FC, __hip_bfloat16><<<cdiv(N, 64), 256, 0, stream>>>(
                h, W2 + (size_t)r * 128 * 64, 64, c0, tmp, N);
            scatter_kernel<FC><<<cdiv(E * (FC / 4), TPB), TPB, 0, stream>>>(
                edges + (size_t)(r * 2 + 0) * E, edges + (size_t)(r * 2 + 1) * E,
                tmp, s + (size_t)(r * 2 + 0) * N, s + (size_t)(r * 2 + 1) * N, out + c0, 64, E);
        }
    }
    relu_kernel<<<cdiv(N * 64, TPB), TPB, 0, stream>>>(out, N * 64);
}

extern "C" void kernel_launch(void* const* d_in, const int* in_sizes, int n_in,
                              void* d_out, int out_size, void* d_ws, size_t ws_size,
                              hipStream_t stream) {
    const float* x  = (const float*)d_in[0];   // [N,128]
    const float* W1 = (const float*)d_in[1];   // [3,128,128]
    const float* b1 = (const float*)d_in[2];   // [3,128]
    const float* W2 = (const float*)d_in[3];   // [3,128,64]
    const float* b2 = (const float*)d_in[4];   // [3,64]
    const int*   edges = (const int*)d_in[5];  // [3,2,E] int32
    float* out = (float*)d_out;                // [N,64]

    const int N = in_sizes[0] / 128;
    const int E = in_sizes[5] / 6;

    const size_t need64 = (size_t)6 * N * 4 + (size_t)N * 128 * 2 + (size_t)N * 64 * 4 + 1024;
    if (ws_size >= need64)
        run_pipeline<64>(x, W1, b1, W2, b2, edges, out, d_ws, N, E, stream);
    else
        run_pipeline<32>(x, W1, b1, W2, b2, edges, out, d_ws, N, E, stream);
}

// Round 3
// 1003.785 us; speedup vs baseline: 2.9444x; 2.9444x over previous
//
#include <hip/hip_runtime.h>
#include <hip/hip_bf16.h>

// RGCN on MI355X — round 3: CSR pull aggregation (no float atomics), bf16 T.
//
// Round-2 post-mortem: 9 scatter dispatches x 260us = 2.34ms of 2.96ms.
// WRITE_SIZE=300MB/dispatch (19.2M f32 atomics write ~16B HBM each).
// Fix: per-relation CSR by dst; gather kernel where each (dst, feat4) is
// owned by one thread -> plain += . T stored bf16 (halves gather bytes).
// ws = 46.8MB (round-2 proved ws_size >= 53.6MB).

constexpr int TPB = 256;

__device__ __forceinline__ float bf2f(unsigned short u) {
    return __uint_as_float(((unsigned)u) << 16);
}

__global__ void count_kernel(const int* __restrict__ edges, unsigned* __restrict__ cnt,
                             int total, int E, int N) {
    int i = blockIdx.x * blockDim.x + threadIdx.x;
    if (i >= total) return;
    atomicAdd(&cnt[(size_t)(i / E) * N + edges[i]], 1u);
}

// One block per relation: exclusive scan of in-degree counts -> off[r][0..N].
__global__ __launch_bounds__(1024) void scan_kernel(const unsigned* __restrict__ cnt,
                                                    int* __restrict__ off, int N) {
    const unsigned* in = cnt + (size_t)(2 * blockIdx.x + 1) * N;  // in-deg slot
    int* o = off + (size_t)blockIdx.x * (N + 1);
    __shared__ unsigned wsum[16];
    __shared__ unsigned carry_s;
    if (threadIdx.x == 0) carry_s = 0;
    __syncthreads();
    const int lane = threadIdx.x & 63, wid = threadIdx.x >> 6;
    for (int c0 = 0; c0 < N; c0 += 1024) {
        int i = c0 + threadIdx.x;
        unsigned v = (i < N) ? in[i] : 0u;
        unsigned x = v;
#pragma unroll
        for (int d = 1; d < 64; d <<= 1) {
            unsigned t = __shfl_up(x, d, 64);
            if (lane >= d) x += t;
        }
        if (lane == 63) wsum[wid] = x;
        __syncthreads();
        unsigned woff = 0, total = 0;
#pragma unroll
        for (int w2 = 0; w2 < 16; ++w2) {
            unsigned t = wsum[w2];
            if (w2 < wid) woff += t;
            total += t;
        }
        if (i < N) o[i] = (int)(carry_s + woff + x - v);  // exclusive
        __syncthreads();
        if (threadIdx.x == 0) carry_s += total;
    }
    if (threadIdx.x == 0) o[N] = (int)carry_s;
}

__global__ void cursor_init_kernel(const int* __restrict__ off, int* __restrict__ cur, int N) {
    int i = blockIdx.x * blockDim.x + threadIdx.x;
    if (i >= 3 * N) return;
    int r = i / N, n = i - r * N;
    cur[i] = off[(size_t)r * (N + 1) + n];
}

__global__ void fill_kernel(const int* __restrict__ edges, int* __restrict__ cur,
                            int* __restrict__ csr_src, int E, int N) {
    int gid = blockIdx.x * blockDim.x + threadIdx.x;
    if (gid >= 3 * E) return;
    int r = gid / E, e = gid - r * E;
    int d  = edges[(size_t)(2 * r + 1) * E + e];
    int sv = edges[(size_t)(2 * r) * E + e];
    int pos = atomicAdd(&cur[(size_t)r * N + d], 1);
    csr_src[(size_t)r * E + pos] = sv;
}

// s[i] = rsqrt(max(cnt[i],1)) in place (after scans consumed the counts).
__global__ void scale_inplace_kernel(unsigned* __restrict__ buf, int total) {
    int i = blockIdx.x * blockDim.x + threadIdx.x;
    if (i >= total) return;
    unsigned c = buf[i];
    ((float*)buf)[i] = rsqrtf((float)(c ? c : 1u));
}

template <int FC>
__global__ void init_bias_kernel(const float* __restrict__ b, int FT, int c0,
                                 float* __restrict__ acc, int N) {
    int i = blockIdx.x * blockDim.x + threadIdx.x;
    if (i >= N * FC) return;
    int j = i & (FC - 1);
    acc[i] = b[c0 + j] + b[FT + c0 + j] + b[2 * FT + c0 + j];
}

__device__ __forceinline__ float to_f(float v) { return v; }
__device__ __forceinline__ float to_f(__hip_bfloat16 v) { return __bfloat162float(v); }

// T[N,FC](bf16) = X[N,128] @ W[128, c0:c0+FC] (W row stride WS). fp32 compute.
template <int FC, typename XT>
__global__ __launch_bounds__(256) void gemm_kernel(const XT* __restrict__ X,
                                                   const float* __restrict__ W, int WS, int c0,
                                                   __hip_bfloat16* __restrict__ T, int N) {
    constexpr int BM = 64, KC = 32, K = 128, TN = FC / 16;
    __shared__ float Xs[BM][KC + 1];
    __shared__ float Bs[KC][FC];

    const int m0 = blockIdx.x * BM;
    const int t  = threadIdx.x;
    const int tr = t >> 4;
    const int tc = t & 15;

    float acc[4][TN];
#pragma unroll
    for (int i = 0; i < 4; ++i)
#pragma unroll
        for (int j = 0; j < TN; ++j) acc[i][j] = 0.f;

    for (int kc = 0; kc < K; kc += KC) {
        for (int i = t; i < BM * KC; i += 256) {
            int r = i >> 5, k = i & 31;
            int row = m0 + r;
            Xs[r][k] = (row < N) ? to_f(X[(size_t)row * K + kc + k]) : 0.f;
        }
        for (int i = t; i < KC * FC; i += 256) {
            int kk = i / FC, c = i % FC;
            Bs[kk][c] = W[(size_t)(kc + kk) * WS + c0 + c];
        }
        __syncthreads();
#pragma unroll
        for (int k = 0; k < KC; ++k) {
            float a[4], bb[TN];
#pragma unroll
            for (int i = 0; i < 4; ++i) a[i] = Xs[tr * 4 + i][k];
#pragma unroll
            for (int j = 0; j < TN; ++j) bb[j] = Bs[k][tc * TN + j];
#pragma unroll
            for (int i = 0; i < 4; ++i)
#pragma unroll
                for (int j = 0; j < TN; ++j) acc[i][j] += a[i] * bb[j];
        }
        __syncthreads();
    }

#pragma unroll
    for (int i = 0; i < 4; ++i) {
        int row = m0 + tr * 4 + i;
        if (row < N) {
            static_assert(TN == 4, "pack assumes TN==4");
            ushort4 pk;
            pk.x = __bfloat16_as_ushort(__float2bfloat16(acc[i][0]));
            pk.y = __bfloat16_as_ushort(__float2bfloat16(acc[i][1]));
            pk.z = __bfloat16_as_ushort(__float2bfloat16(acc[i][2]));
            pk.w = __bfloat16_as_ushort(__float2bfloat16(acc[i][3]));
            *reinterpret_cast<ushort4*>(&T[(size_t)row * FC + tc * TN]) = pk;
        }
    }
}

// acc[n*FC + j..j+3] += s_in[n] * sum_{e in CSR[n]} s_out[src_e] * T[src_e, j..j+3]
template <int FC>
__global__ void gather_kernel(const int* __restrict__ off, const int* __restrict__ csr_src,
                              const __hip_bfloat16* __restrict__ T,
                              const float* __restrict__ s_out, const float* __restrict__ s_in,
                              float* __restrict__ acc, int N) {
    constexpr int LPN = FC / 4;
    int gid = blockIdx.x * blockDim.x + threadIdx.x;
    int n = gid / LPN;
    if (n >= N) return;
    int j = (gid & (LPN - 1)) * 4;
    int e0 = off[n], e1 = off[n + 1];
    float sx = 0.f, sy = 0.f, sz = 0.f, sw = 0.f;
    for (int e = e0; e < e1; ++e) {
        int sN = csr_src[e];
        float w = s_out[sN];
        ushort4 raw = *reinterpret_cast<const ushort4*>(&T[(size_t)sN * FC + j]);
        sx += w * bf2f(raw.x);
        sy += w * bf2f(raw.y);
        sz += w * bf2f(raw.z);
        sw += w * bf2f(raw.w);
    }
    float si = s_in[n];
    float* p = &acc[(size_t)n * FC + j];
    p[0] += sx * si;
    p[1] += sy * si;
    p[2] += sz * si;
    p[3] += sw * si;
}

template <int FC>
__global__ void relu_store_h_kernel(const float* __restrict__ acc, __hip_bfloat16* __restrict__ h,
                                    int c0, int N) {
    int i = blockIdx.x * blockDim.x + threadIdx.x;
    if (i >= N * FC) return;
    int n = i / FC, j = i & (FC - 1);
    h[(size_t)n * 128 + c0 + j] = __float2bfloat16(fmaxf(acc[i], 0.f));
}

__global__ void relu_kernel(float* __restrict__ a, int total) {
    int i = blockIdx.x * blockDim.x + threadIdx.x;
    if (i >= total) return;
    a[i] = fmaxf(a[i], 0.f);
}

static inline int cdiv(int a, int b) { return (a + b - 1) / b; }

extern "C" void kernel_launch(void* const* d_in, const int* in_sizes, int n_in,
                              void* d_out, int out_size, void* d_ws, size_t ws_size,
                              hipStream_t stream) {
    const float* x  = (const float*)d_in[0];   // [N,128]
    const float* W1 = (const float*)d_in[1];   // [3,128,128]
    const float* b1 = (const float*)d_in[2];   // [3,128]
    const float* W2 = (const float*)d_in[3];   // [3,128,64]
    const float* b2 = (const float*)d_in[4];   // [3,64]
    const int*   edges = (const int*)d_in[5];  // [3,2,E] int32
    float* out = (float*)d_out;                // [N,64]

    const int N = in_sizes[0] / 128;
    const int E = in_sizes[5] / 6;

    // ws layout (46.8MB total; round-2 profile proved ws_size >= 53.6MB):
    auto align256 = [](char* p) { return (char*)(((uintptr_t)p + 255) & ~(uintptr_t)255); };
    char* w = (char*)d_ws;
    unsigned* cnt = (unsigned*)w;               // aliased with s
    float* s = (float*)w;                       w = align256(w + (size_t)6 * N * 4);
    __hip_bfloat16* h = (__hip_bfloat16*)w;     w = align256(w + (size_t)N * 128 * 2);
    __hip_bfloat16* T = (__hip_bfloat16*)w;     w = align256(w + (size_t)N * 64 * 2);
    int* off = (int*)w;                         w = align256(w + (size_t)3 * (N + 1) * 4);
    int* cur = (int*)w;                         w = align256(w + (size_t)3 * N * 4);
    int* csr = (int*)w;

    // ---- graph preprocessing ----
    hipMemsetAsync(cnt, 0, (size_t)6 * N * 4, stream);
    count_kernel<<<cdiv(6 * E, TPB), TPB, 0, stream>>>(edges, cnt, 6 * E, E, N);
    scan_kernel<<<3, 1024, 0, stream>>>(cnt, off, N);
    cursor_init_kernel<<<cdiv(3 * N, TPB), TPB, 0, stream>>>(off, cur, N);
    fill_kernel<<<cdiv(3 * E, TPB), TPB, 0, stream>>>(edges, cur, csr, E, N);
    scale_inplace_kernel<<<cdiv(6 * N, TPB), TPB, 0, stream>>>(cnt, 6 * N);

    // ---- layer 1: 128 -> 128 in two 64-wide chunks, acc aliased into d_out ----
    for (int c0 = 0; c0 < 128; c0 += 64) {
        init_bias_kernel<64><<<cdiv(N * 64, TPB), TPB, 0, stream>>>(b1, 128, c0, out, N);
        for (int r = 0; r < 3; ++r) {
            gemm_kernel<64, float><<<cdiv(N, 64), 256, 0, stream>>>(
                x, W1 + (size_t)r * 128 * 128, 128, c0, T, N);
            gather_kernel<64><<<cdiv(N * 16, TPB), TPB, 0, stream>>>(
                off + (size_t)r * (N + 1), csr + (size_t)r * E, T,
                s + (size_t)(2 * r) * N, s + (size_t)(2 * r + 1) * N, out, N);
        }
        relu_store_h_kernel<64><<<cdiv(N * 64, TPB), TPB, 0, stream>>>(out, h, c0, N);
    }

    // ---- layer 2: 128 -> 64, acc directly in d_out ----
    init_bias_kernel<64><<<cdiv(N * 64, TPB), TPB, 0, stream>>>(b2, 64, 0, out, N);
    for (int r = 0; r < 3; ++r) {
        gemm_kernel<64, __hip_bfloat16><<<cdiv(N, 64), 256, 0, stream>>>(
            h, W2 + (size_t)r * 128 * 64, 64, 0, T, N);
        gather_kernel<64><<<cdiv(N * 16, TPB), TPB, 0, stream>>>(
            off + (size_t)r * (N + 1), csr + (size_t)r * E, T,
            s + (size_t)(2 * r) * N, s + (size_t)(2 * r + 1) * N, out, N);
    }
    relu_kernel<<<cdiv(N * 64, TPB), TPB, 0, stream>>>(out, N * 64);
}

// Round 4
// 536.707 us; speedup vs baseline: 5.5069x; 1.8703x over previous
//
#include <hip/hip_runtime.h>
#include <hip/hip_bf16.h>
#include <stdint.h>

// RGCN on MI355X — round 4: MFMA bf16 GEMM + fast hierarchical scan + fused gather.
//
// Round-3 post-mortem: scan_kernel 85us (3 blocks, serial); fp32 GEMMs ~45us ea;
// gathers ~30us ea. Fixes: (1) 16x16x32 bf16 MFMA GEMM, W staged in fragment-
// layout LDS, A-frags from global w/ inline f32->bf16; (2) 3-kernel scan;
// (3) gather phases fuse bias-init and relu/h-store, killing 9 elementwise passes.

constexpr int TPB = 256;

typedef __attribute__((ext_vector_type(8))) short short8;
typedef __attribute__((ext_vector_type(4))) float f32x4;

__device__ __forceinline__ float bf2f(unsigned short u) {
    return __uint_as_float(((unsigned)u) << 16);
}
__device__ __forceinline__ unsigned short f2bf(float f) {
    return __bfloat16_as_ushort(__float2bfloat16(f));
}

// ---------------- graph preprocessing ----------------

__global__ void count_kernel(const int* __restrict__ edges, unsigned* __restrict__ cnt,
                             int total, int E, int N) {
    int i = blockIdx.x * blockDim.x + threadIdx.x;
    if (i >= total) return;
    atomicAdd(&cnt[(size_t)(i / E) * N + edges[i]], 1u);
}

// Local exclusive scan of 1024-element tiles of the in-degree counts.
__global__ __launch_bounds__(256) void scan_local_kernel(const unsigned* __restrict__ cnt,
                                                         int* __restrict__ off,
                                                         unsigned* __restrict__ bsum,
                                                         int N, int nb) {
    int r = blockIdx.x / nb, blk = blockIdx.x - r * nb;
    const unsigned* in = cnt + (size_t)(2 * r + 1) * N;  // in-degree slot
    int* o = off + (size_t)r * (N + 1);
    const int t = threadIdx.x, lane = t & 63, wid = t >> 6;
    int base = blk * 1024 + t * 4;
    unsigned v0 = (base + 0 < N) ? in[base + 0] : 0u;
    unsigned v1 = (base + 1 < N) ? in[base + 1] : 0u;
    unsigned v2 = (base + 2 < N) ? in[base + 2] : 0u;
    unsigned v3 = (base + 3 < N) ? in[base + 3] : 0u;
    unsigned p1 = v0, p2 = p1 + v1, p3 = p2 + v2, tt = p3 + v3;
    unsigned x = tt;
#pragma unroll
    for (int d = 1; d < 64; d <<= 1) {
        unsigned tmp = __shfl_up(x, d, 64);
        if (lane >= d) x += tmp;
    }
    __shared__ unsigned ws4[4];
    if (lane == 63) ws4[wid] = x;
    __syncthreads();
    unsigned woff = 0;
#pragma unroll
    for (int w2 = 0; w2 < 4; ++w2)
        if (w2 < wid) woff += ws4[w2];
    unsigned excl = woff + x - tt;
    if (base + 0 < N) o[base + 0] = (int)excl;
    if (base + 1 < N) o[base + 1] = (int)(excl + p1);
    if (base + 2 < N) o[base + 2] = (int)(excl + p2);
    if (base + 3 < N) o[base + 3] = (int)(excl + p3);
    if (t == 255) bsum[r * nb + blk] = woff + x;
}

// One block: exclusive scan of per-tile sums for each relation (nb <= 128).
__global__ __launch_bounds__(128) void scan_bsum_kernel(unsigned* __restrict__ bsum,
                                                        int* __restrict__ off,
                                                        int nb, int N, int E) {
    const int t = threadIdx.x, lane = t & 63, wid = t >> 6;
    __shared__ unsigned wtot[2];
    for (int r = 0; r < 3; ++r) {
        unsigned v = (t < nb) ? bsum[r * nb + t] : 0u;
        unsigned x = v;
#pragma unroll
        for (int d = 1; d < 64; d <<= 1) {
            unsigned tmp = __shfl_up(x, d, 64);
            if (lane >= d) x += tmp;
        }
        if (lane == 63) wtot[wid] = x;
        __syncthreads();
        unsigned add = (wid == 1) ? wtot[0] : 0u;
        if (t < nb) bsum[r * nb + t] = add + x - v;  // exclusive
        if (t == 0) off[(size_t)r * (N + 1) + N] = E;  // total in-degree == E
        __syncthreads();
    }
}

// off += tile offset; also init cursors.
__global__ void finalize_off_kernel(int* __restrict__ off, const unsigned* __restrict__ bsum,
                                    int* __restrict__ cur, int N, int nb) {
    int i = blockIdx.x * blockDim.x + threadIdx.x;
    if (i >= 3 * N) return;
    int r = i / N, n = i - r * N;
    int v = off[(size_t)r * (N + 1) + n] + (int)bsum[r * nb + (n >> 10)];
    off[(size_t)r * (N + 1) + n] = v;
    cur[i] = v;
}

__global__ void fill_kernel(const int* __restrict__ edges, int* __restrict__ cur,
                            int* __restrict__ csr_src, int E, int N) {
    int gid = blockIdx.x * blockDim.x + threadIdx.x;
    if (gid >= 3 * E) return;
    int r = gid / E, e = gid - r * E;
    int d  = edges[(size_t)(2 * r + 1) * E + e];
    int sv = edges[(size_t)(2 * r) * E + e];
    int pos = atomicAdd(&cur[(size_t)r * N + d], 1);
    csr_src[(size_t)r * E + pos] = sv;
}

__global__ void scale_inplace_kernel(unsigned* __restrict__ buf, int total) {
    int i = blockIdx.x * blockDim.x + threadIdx.x;
    if (i >= total) return;
    unsigned c = buf[i];
    ((float*)buf)[i] = rsqrtf((float)(c ? c : 1u));
}

// ---------------- MFMA GEMM:  T[N,64](bf16) = X[N,128] @ W[128, c0:c0+64] ----------------
// Block: 64 rows, 256 threads (4 waves); wave w owns rows [16w,16w+16), all 64 cols.
// W chunk staged once into LDS in MFMA B-fragment layout (1 ds_read_b128 per frag,
// conflict-free). A-fragments loaded directly from global (f32->bf16 inline).
// Layouts (guide §3, m89-verified C/D): A: row=lane&15, k=(lane>>4)*8+j;
// B: col=lane&15, k=(lane>>4)*8+j; D: col=lane&15, row=(lane>>4)*4+reg.

template <typename XT>
__global__ __launch_bounds__(256) void mfma_gemm_kernel(const XT* __restrict__ X,
                                                        const float* __restrict__ W,
                                                        int WS, int c0,
                                                        __hip_bfloat16* __restrict__ T, int N) {
    __shared__ short bs[8192];  // 16 frags (kk,c) x 64 lanes x 8 bf16
    const int t = threadIdx.x;
    const int lane = t & 63, wv = t >> 6;
    const int m0 = blockIdx.x * 64;

    // stage W[128 x 64] chunk -> fragment-layout LDS
#pragma unroll
    for (int i = 0; i < 8; ++i) {
        int linear = i * 256 + t;          // [0,2048): (r4, cc)
        int cc = linear & 63, r4 = linear >> 6;
        int r = r4 << 2;
        const float* wp = W + (size_t)r * WS + c0 + cc;
        unsigned u0 = f2bf(wp[0]);
        unsigned u1 = f2bf(wp[WS]);
        unsigned u2 = f2bf(wp[2 * WS]);
        unsigned u3 = f2bf(wp[3 * WS]);
        int kk = r4 >> 3, jg = (r4 >> 1) & 3, j0 = (r4 & 1) * 4;
        int l = jg * 16 + (cc & 15), c = cc >> 4;
        int slot = (((kk << 2) | c) << 9) + l * 8 + j0;
        *reinterpret_cast<uint2*>(&bs[slot]) = make_uint2(u0 | (u1 << 16), u2 | (u3 << 16));
    }

    // A fragments from global (row per lane&15, k-group per lane>>4)
    const int row = m0 + wv * 16 + (lane & 15);
    const bool ok = row < N;
    short8 a[4];
    if constexpr (sizeof(XT) == 4) {  // f32 input
        const float* xr = (const float*)X + (size_t)row * 128 + ((lane >> 4) << 3);
#pragma unroll
        for (int kk = 0; kk < 4; ++kk) {
            short8 av = {};
            if (ok) {
                float4 f0 = *reinterpret_cast<const float4*>(xr + kk * 32);
                float4 f1 = *reinterpret_cast<const float4*>(xr + kk * 32 + 4);
                av[0] = (short)f2bf(f0.x); av[1] = (short)f2bf(f0.y);
                av[2] = (short)f2bf(f0.z); av[3] = (short)f2bf(f0.w);
                av[4] = (short)f2bf(f1.x); av[5] = (short)f2bf(f1.y);
                av[6] = (short)f2bf(f1.z); av[7] = (short)f2bf(f1.w);
            }
            a[kk] = av;
        }
    } else {  // bf16 input
        const short* xr = (const short*)X + (size_t)row * 128 + ((lane >> 4) << 3);
#pragma unroll
        for (int kk = 0; kk < 4; ++kk) {
            short8 av = {};
            if (ok) av = *reinterpret_cast<const short8*>(xr + kk * 32);
            a[kk] = av;
        }
    }

    __syncthreads();

    f32x4 acc4[4] = {{0.f, 0.f, 0.f, 0.f}, {0.f, 0.f, 0.f, 0.f},
                     {0.f, 0.f, 0.f, 0.f}, {0.f, 0.f, 0.f, 0.f}};
#pragma unroll
    for (int c = 0; c < 4; ++c) {
#pragma unroll
        for (int kk = 0; kk < 4; ++kk) {
            short8 b = *reinterpret_cast<const short8*>(&bs[(((kk << 2) | c) << 9) + lane * 8]);
            acc4[c] = __builtin_amdgcn_mfma_f32_16x16x32_bf16(a[kk], b, acc4[c], 0, 0, 0);
        }
    }

#pragma unroll
    for (int c = 0; c < 4; ++c) {
        int gcol = c * 16 + (lane & 15);
#pragma unroll
        for (int q = 0; q < 4; ++q) {
            int grow = m0 + wv * 16 + ((lane >> 4) << 2) + q;
            if (grow < N) T[(size_t)grow * 64 + gcol] = __float2bfloat16(acc4[c][q]);
        }
    }
}

// ---------------- fused gather ----------------
// PHASE 0: acc = bias_sum + si*sum      (no acc read; kills init_bias)
// PHASE 1: acc += si*sum
// PHASE 2: h[n,c0+j] = bf16(relu(acc + si*sum))   (layer-1 final; no acc write-back)
// PHASE 3: acc = relu(acc + si*sum)               (layer-2 final)

template <int PHASE>
__global__ __launch_bounds__(256) void gather_kernel(const int* __restrict__ off,
                                                     const int* __restrict__ csr_src,
                                                     const __hip_bfloat16* __restrict__ T,
                                                     const float* __restrict__ s_out,
                                                     const float* __restrict__ s_in,
                                                     float* __restrict__ acc,
                                                     const float* __restrict__ b, int FT, int c0,
                                                     __hip_bfloat16* __restrict__ h, int N) {
    int gid = blockIdx.x * blockDim.x + threadIdx.x;
    int n = gid >> 4;
    if (n >= N) return;
    int j = (gid & 15) << 2;
    int e0 = off[n], e1 = off[n + 1];
    float sx = 0.f, sy = 0.f, sz = 0.f, sw = 0.f;
    for (int e = e0; e < e1; ++e) {
        int sN = csr_src[e];
        float w = s_out[sN];
        ushort4 raw = *reinterpret_cast<const ushort4*>(&T[(size_t)sN * 64 + j]);
        sx += w * bf2f(raw.x);
        sy += w * bf2f(raw.y);
        sz += w * bf2f(raw.z);
        sw += w * bf2f(raw.w);
    }
    float si = s_in[n];
    float4* p = reinterpret_cast<float4*>(&acc[(size_t)n * 64 + j]);
    if constexpr (PHASE == 0) {
        int bj = c0 + j;
        float4 o;
        o.x = b[bj + 0] + b[FT + bj + 0] + b[2 * FT + bj + 0] + sx * si;
        o.y = b[bj + 1] + b[FT + bj + 1] + b[2 * FT + bj + 1] + sy * si;
        o.z = b[bj + 2] + b[FT + bj + 2] + b[2 * FT + bj + 2] + sz * si;
        o.w = b[bj + 3] + b[FT + bj + 3] + b[2 * FT + bj + 3] + sw * si;
        *p = o;
    } else if constexpr (PHASE == 1) {
        float4 v = *p;
        v.x += sx * si; v.y += sy * si; v.z += sz * si; v.w += sw * si;
        *p = v;
    } else if constexpr (PHASE == 2) {
        float4 v = *p;
        ushort4 o;
        o.x = f2bf(fmaxf(v.x + sx * si, 0.f));
        o.y = f2bf(fmaxf(v.y + sy * si, 0.f));
        o.z = f2bf(fmaxf(v.z + sz * si, 0.f));
        o.w = f2bf(fmaxf(v.w + sw * si, 0.f));
        *reinterpret_cast<ushort4*>(&h[(size_t)n * 128 + c0 + j]) = o;
    } else {
        float4 v = *p;
        v.x = fmaxf(v.x + sx * si, 0.f);
        v.y = fmaxf(v.y + sy * si, 0.f);
        v.z = fmaxf(v.z + sz * si, 0.f);
        v.w = fmaxf(v.w + sw * si, 0.f);
        *p = v;
    }
}

static inline int cdiv(int a, int b) { return (a + b - 1) / b; }

extern "C" void kernel_launch(void* const* d_in, const int* in_sizes, int n_in,
                              void* d_out, int out_size, void* d_ws, size_t ws_size,
                              hipStream_t stream) {
    const float* x  = (const float*)d_in[0];   // [N,128]
    const float* W1 = (const float*)d_in[1];   // [3,128,128]
    const float* b1 = (const float*)d_in[2];   // [3,128]
    const float* W2 = (const float*)d_in[3];   // [3,128,64]
    const float* b2 = (const float*)d_in[4];   // [3,64]
    const int*   edges = (const int*)d_in[5];  // [3,2,E] int32
    float* out = (float*)d_out;                // [N,64]

    const int N = in_sizes[0] / 128;
    const int E = in_sizes[5] / 6;
    const int nb = cdiv(N, 1024);

    // ws layout (~46.9MB; round-2 proved ws_size >= 53.6MB)
    auto align256 = [](char* p) { return (char*)(((uintptr_t)p + 255) & ~(uintptr_t)255); };
    char* w = (char*)d_ws;
    unsigned* cnt = (unsigned*)w;               // aliased with s
    float* s = (float*)w;                       w = align256(w + (size_t)6 * N * 4);
    __hip_bfloat16* h = (__hip_bfloat16*)w;     w = align256(w + (size_t)N * 128 * 2);
    __hip_bfloat16* T = (__hip_bfloat16*)w;     w = align256(w + (size_t)N * 64 * 2);
    int* off = (int*)w;                         w = align256(w + (size_t)3 * (N + 1) * 4);
    int* cur = (int*)w;                         w = align256(w + (size_t)3 * N * 4);
    int* csr = (int*)w;                         w = align256(w + (size_t)3 * E * 4);
    unsigned* bsum = (unsigned*)w;

    // ---- graph preprocessing ----
    hipMemsetAsync(cnt, 0, (size_t)6 * N * 4, stream);
    count_kernel<<<cdiv(6 * E, TPB), TPB, 0, stream>>>(edges, cnt, 6 * E, E, N);
    scan_local_kernel<<<3 * nb, 256, 0, stream>>>(cnt, off, bsum, N, nb);
    scan_bsum_kernel<<<1, 128, 0, stream>>>(bsum, off, nb, N, E);
    finalize_off_kernel<<<cdiv(3 * N, TPB), TPB, 0, stream>>>(off, bsum, cur, N, nb);
    fill_kernel<<<cdiv(3 * E, TPB), TPB, 0, stream>>>(edges, cur, csr, E, N);
    scale_inplace_kernel<<<cdiv(6 * N, TPB), TPB, 0, stream>>>(cnt, 6 * N);

    const int ggrid = cdiv(N * 16, TPB);
    const int mgrid = cdiv(N, 64);

    // ---- layer 1: 128 -> 128 in two 64-col chunks; acc = d_out (scratch) ----
    for (int c0 = 0; c0 < 128; c0 += 64) {
        for (int r = 0; r < 3; ++r) {
            mfma_gemm_kernel<float><<<mgrid, 256, 0, stream>>>(
                x, W1 + (size_t)r * 128 * 128, 128, c0, T, N);
            const int* offr = off + (size_t)r * (N + 1);
            const int* csrr = csr + (size_t)r * E;
            const float* so = s + (size_t)(2 * r) * N;
            const float* si = s + (size_t)(2 * r + 1) * N;
            if (r == 0)
                gather_kernel<0><<<ggrid, TPB, 0, stream>>>(offr, csrr, T, so, si, out, b1, 128, c0, h, N);
            else if (r == 1)
                gather_kernel<1><<<ggrid, TPB, 0, stream>>>(offr, csrr, T, so, si, out, b1, 128, c0, h, N);
            else
                gather_kernel<2><<<ggrid, TPB, 0, stream>>>(offr, csrr, T, so, si, out, b1, 128, c0, h, N);
        }
    }

    // ---- layer 2: 128 -> 64; acc = d_out (final) ----
    for (int r = 0; r < 3; ++r) {
        mfma_gemm_kernel<__hip_bfloat16><<<mgrid, 256, 0, stream>>>(
            h, W2 + (size_t)r * 128 * 64, 64, 0, T, N);
        const int* offr = off + (size_t)r * (N + 1);
        const int* csrr = csr + (size_t)r * E;
        const float* so = s + (size_t)(2 * r) * N;
        const float* si = s + (size_t)(2 * r + 1) * N;
        if (r == 0)
            gather_kernel<0><<<ggrid, TPB, 0, stream>>>(offr, csrr, T, so, si, out, b2, 64, 0, h, N);
        else if (r == 1)
            gather_kernel<1><<<ggrid, TPB, 0, stream>>>(offr, csrr, T, so, si, out, b2, 64, 0, h, N);
        else
            gather_kernel<3><<<ggrid, TPB, 0, stream>>>(offr, csrr, T, so, si, out, b2, 64, 0, h, N);
    }
}

// Round 5
// 495.886 us; speedup vs baseline: 5.9602x; 1.0823x over previous
//
#include <hip/hip_runtime.h>
#include <hip/hip_bf16.h>
#include <stdint.h>

// RGCN on MI355X — round 5: fuse 3 relations into single GEMM + single gather
// per column-chunk. Kills the f32 accumulator round-trips (~345MB), reads x
// once per chunk, drops 18 dispatches -> 6 (CH=64) or 12 (CH=32).
//
// Round-4 post-mortem: count 70us (atomic-bound, keep); gathers ~250us total
// dominated by acc R/W between relation phases; GEMMs re-read x 3x.
// ws: CH=64 path needs 71.2MB (branch on ws_size); CH=32 path fits 52.0MB
// (known-safe: round-2 proved ws_size >= 53.6MB). cur/bsum alias into T.

constexpr int TPB = 256;

typedef __attribute__((ext_vector_type(8))) short short8;
typedef __attribute__((ext_vector_type(4))) float f32x4;

__device__ __forceinline__ float bf2f(unsigned short u) {
    return __uint_as_float(((unsigned)u) << 16);
}
__device__ __forceinline__ unsigned short f2bf(float f) {
    return __bfloat16_as_ushort(__float2bfloat16(f));
}

// ---------------- graph preprocessing ----------------

__global__ void count_kernel(const int* __restrict__ edges, unsigned* __restrict__ cnt,
                             int total, int E, int N) {
    int i = blockIdx.x * blockDim.x + threadIdx.x;
    if (i >= total) return;
    atomicAdd(&cnt[(size_t)(i / E) * N + edges[i]], 1u);
}

__global__ __launch_bounds__(256) void scan_local_kernel(const unsigned* __restrict__ cnt,
                                                         int* __restrict__ off,
                                                         unsigned* __restrict__ bsum,
                                                         int N, int nb) {
    int r = blockIdx.x / nb, blk = blockIdx.x - r * nb;
    const unsigned* in = cnt + (size_t)(2 * r + 1) * N;  // in-degree slot
    int* o = off + (size_t)r * (N + 1);
    const int t = threadIdx.x, lane = t & 63, wid = t >> 6;
    int base = blk * 1024 + t * 4;
    unsigned v0 = (base + 0 < N) ? in[base + 0] : 0u;
    unsigned v1 = (base + 1 < N) ? in[base + 1] : 0u;
    unsigned v2 = (base + 2 < N) ? in[base + 2] : 0u;
    unsigned v3 = (base + 3 < N) ? in[base + 3] : 0u;
    unsigned p1 = v0, p2 = p1 + v1, p3 = p2 + v2, tt = p3 + v3;
    unsigned x = tt;
#pragma unroll
    for (int d = 1; d < 64; d <<= 1) {
        unsigned tmp = __shfl_up(x, d, 64);
        if (lane >= d) x += tmp;
    }
    __shared__ unsigned ws4[4];
    if (lane == 63) ws4[wid] = x;
    __syncthreads();
    unsigned woff = 0;
#pragma unroll
    for (int w2 = 0; w2 < 4; ++w2)
        if (w2 < wid) woff += ws4[w2];
    unsigned excl = woff + x - tt;
    if (base + 0 < N) o[base + 0] = (int)excl;
    if (base + 1 < N) o[base + 1] = (int)(excl + p1);
    if (base + 2 < N) o[base + 2] = (int)(excl + p2);
    if (base + 3 < N) o[base + 3] = (int)(excl + p3);
    if (t == 255) bsum[r * nb + blk] = woff + x;
}

__global__ __launch_bounds__(128) void scan_bsum_kernel(unsigned* __restrict__ bsum,
                                                        int* __restrict__ off,
                                                        int nb, int N, int E) {
    const int t = threadIdx.x, lane = t & 63, wid = t >> 6;
    __shared__ unsigned wtot[2];
    for (int r = 0; r < 3; ++r) {
        unsigned v = (t < nb) ? bsum[r * nb + t] : 0u;
        unsigned x = v;
#pragma unroll
        for (int d = 1; d < 64; d <<= 1) {
            unsigned tmp = __shfl_up(x, d, 64);
            if (lane >= d) x += tmp;
        }
        if (lane == 63) wtot[wid] = x;
        __syncthreads();
        unsigned add = (wid == 1) ? wtot[0] : 0u;
        if (t < nb) bsum[r * nb + t] = add + x - v;  // exclusive
        if (t == 0) off[(size_t)r * (N + 1) + N] = E;
        __syncthreads();
    }
}

__global__ void finalize_off_kernel(int* __restrict__ off, const unsigned* __restrict__ bsum,
                                    int* __restrict__ cur, int N, int nb) {
    int i = blockIdx.x * blockDim.x + threadIdx.x;
    if (i >= 3 * N) return;
    int r = i / N, n = i - r * N;
    int v = off[(size_t)r * (N + 1) + n] + (int)bsum[r * nb + (n >> 10)];
    off[(size_t)r * (N + 1) + n] = v;
    cur[i] = v;
}

__global__ void fill_kernel(const int* __restrict__ edges, int* __restrict__ cur,
                            int* __restrict__ csr_src, int E, int N) {
    int gid = blockIdx.x * blockDim.x + threadIdx.x;
    if (gid >= 3 * E) return;
    int r = gid / E, e = gid - r * E;
    int d  = edges[(size_t)(2 * r + 1) * E + e];
    int sv = edges[(size_t)(2 * r) * E + e];
    int pos = atomicAdd(&cur[(size_t)r * N + d], 1);
    csr_src[(size_t)r * E + pos] = sv;
}

__global__ void scale_inplace_kernel(unsigned* __restrict__ buf, int total) {
    int i = blockIdx.x * blockDim.x + threadIdx.x;
    if (i >= total) return;
    unsigned c = buf[i];
    ((float*)buf)[i] = rsqrtf((float)(c ? c : 1u));
}

// ---------------- fused 3-relation MFMA GEMM ----------------
// T_r[N,CH](bf16) = X[N,128] @ W[r][128, c0:c0+CH], r=0..2, one dispatch.
// Block: 64 rows, 4 waves; wave wv owns rows [16wv,16wv+16), all 3*CH cols.
// All 3 W chunks staged in MFMA B-fragment layout (conflict-free ds_read_b128).
// Layouts (m89-verified, round-4 validated): A: row=lane&15, k=(lane>>4)*8+j;
// B: col=lane&15, same k; D: col=lane&15, row=(lane>>4)*4+reg.

template <int CH, typename XT>
__global__ __launch_bounds__(256) void mfma_gemm3_kernel(const XT* __restrict__ X,
                                                         const float* __restrict__ W,
                                                         int WS, int c0,
                                                         __hip_bfloat16* __restrict__ T, int N) {
    constexpr int CT = CH / 16;   // col-tiles per relation
    constexpr int FR = 4 * CT;    // frags per relation
    __shared__ short bs[3 * FR * 512];
    const int t = threadIdx.x;
    const int lane = t & 63, wv = t >> 6;
    const int m0 = blockIdx.x * 64;

    // stage W chunks of all 3 relations -> fragment-layout LDS
    constexpr int TOT = 3 * 32 * CH;  // (rel, r4, cc): each entry covers 4 W-rows
    for (int linear = t; linear < TOT; linear += 256) {
        int rrel = linear / (32 * CH);
        int rem = linear - rrel * (32 * CH);
        int r4 = rem / CH, cc = rem - r4 * CH;
        int r = r4 << 2;
        const float* wp = W + (size_t)rrel * 128 * WS + (size_t)r * WS + c0 + cc;
        unsigned u0 = f2bf(wp[0]);
        unsigned u1 = f2bf(wp[WS]);
        unsigned u2 = f2bf(wp[2 * WS]);
        unsigned u3 = f2bf(wp[3 * WS]);
        int kk = r4 >> 3, jg = (r4 >> 1) & 3, j0 = (r4 & 1) * 4;
        int l = jg * 16 + (cc & 15), c = cc >> 4;
        int slot = ((rrel * FR + kk * CT + c) << 9) + l * 8 + j0;
        *reinterpret_cast<uint2*>(&bs[slot]) = make_uint2(u0 | (u1 << 16), u2 | (u3 << 16));
    }

    // A fragments straight from global (f32->bf16 inline for layer 1)
    const int row = m0 + wv * 16 + (lane & 15);
    const bool ok = row < N;
    short8 a[4];
    if constexpr (sizeof(XT) == 4) {
        const float* xr = (const float*)X + (size_t)row * 128 + ((lane >> 4) << 3);
#pragma unroll
        for (int kk = 0; kk < 4; ++kk) {
            short8 av = {};
            if (ok) {
                float4 f0 = *reinterpret_cast<const float4*>(xr + kk * 32);
                float4 f1 = *reinterpret_cast<const float4*>(xr + kk * 32 + 4);
                av[0] = (short)f2bf(f0.x); av[1] = (short)f2bf(f0.y);
                av[2] = (short)f2bf(f0.z); av[3] = (short)f2bf(f0.w);
                av[4] = (short)f2bf(f1.x); av[5] = (short)f2bf(f1.y);
                av[6] = (short)f2bf(f1.z); av[7] = (short)f2bf(f1.w);
            }
            a[kk] = av;
        }
    } else {
        const short* xr = (const short*)X + (size_t)row * 128 + ((lane >> 4) << 3);
#pragma unroll
        for (int kk = 0; kk < 4; ++kk) {
            short8 av = {};
            if (ok) av = *reinterpret_cast<const short8*>(xr + kk * 32);
            a[kk] = av;
        }
    }

    __syncthreads();

    f32x4 acc4[3 * CT];
#pragma unroll
    for (int f = 0; f < 3 * CT; ++f) acc4[f] = {0.f, 0.f, 0.f, 0.f};
#pragma unroll
    for (int rrel = 0; rrel < 3; ++rrel) {
#pragma unroll
        for (int c = 0; c < CT; ++c) {
#pragma unroll
            for (int kk = 0; kk < 4; ++kk) {
                short8 b = *reinterpret_cast<const short8*>(
                    &bs[((rrel * FR + kk * CT + c) << 9) + lane * 8]);
                acc4[rrel * CT + c] =
                    __builtin_amdgcn_mfma_f32_16x16x32_bf16(a[kk], b, acc4[rrel * CT + c], 0, 0, 0);
            }
        }
    }

#pragma unroll
    for (int rrel = 0; rrel < 3; ++rrel) {
        __hip_bfloat16* Tr = T + (size_t)rrel * N * CH;
#pragma unroll
        for (int c = 0; c < CT; ++c) {
            int gcol = c * 16 + (lane & 15);
            f32x4 v = acc4[rrel * CT + c];
#pragma unroll
            for (int q = 0; q < 4; ++q) {
                int grow = m0 + wv * 16 + ((lane >> 4) << 2) + q;
                if (grow < N) Tr[(size_t)grow * CH + gcol] = __float2bfloat16(v[q]);
            }
        }
    }
}

// ---------------- fused 3-relation gather ----------------
// Per node n, CH/4 threads each own 4 cols. Registers accumulate
// bias_sum + sum_r s_in_r[n] * sum_e s_out_r[src] * T_r[src, j..j+3],
// then PHASE 0: h[n, c0+j] = bf16(relu(.)); PHASE 1: out[n, c0+j] = relu(.).

template <int CH, int PHASE>
__global__ __launch_bounds__(256) void gather3_kernel(const int* __restrict__ off,
                                                      const int* __restrict__ csr,
                                                      const __hip_bfloat16* __restrict__ T,
                                                      const float* __restrict__ s,
                                                      const float* __restrict__ b, int FT, int c0,
                                                      float* __restrict__ outp,
                                                      __hip_bfloat16* __restrict__ h,
                                                      int N, int E) {
    constexpr int LPN = CH / 4;
    int gid = blockIdx.x * blockDim.x + threadIdx.x;
    int n = gid / LPN;
    if (n >= N) return;
    int j = (gid % LPN) * 4;
    int bj = c0 + j;
    float ox = b[bj + 0] + b[FT + bj + 0] + b[2 * FT + bj + 0];
    float oy = b[bj + 1] + b[FT + bj + 1] + b[2 * FT + bj + 1];
    float oz = b[bj + 2] + b[FT + bj + 2] + b[2 * FT + bj + 2];
    float ow = b[bj + 3] + b[FT + bj + 3] + b[2 * FT + bj + 3];
#pragma unroll
    for (int r = 0; r < 3; ++r) {
        const int* offr = off + (size_t)r * (N + 1);
        const int* csrr = csr + (size_t)r * E;
        const float* s_out = s + (size_t)(2 * r) * N;
        const __hip_bfloat16* Tr = T + (size_t)r * N * CH;
        int e0 = offr[n], e1 = offr[n + 1];
        float sx = 0.f, sy = 0.f, sz = 0.f, sw = 0.f;
        for (int e = e0; e < e1; ++e) {
            int sN = csrr[e];
            float w = s_out[sN];
            ushort4 raw = *reinterpret_cast<const ushort4*>(&Tr[(size_t)sN * CH + j]);
            sx += w * bf2f(raw.x);
            sy += w * bf2f(raw.y);
            sz += w * bf2f(raw.z);
            sw += w * bf2f(raw.w);
        }
        float si = s[(size_t)(2 * r + 1) * N + n];
        ox += si * sx; oy += si * sy; oz += si * sz; ow += si * sw;
    }
    if constexpr (PHASE == 0) {
        ushort4 o;
        o.x = f2bf(fmaxf(ox, 0.f));
        o.y = f2bf(fmaxf(oy, 0.f));
        o.z = f2bf(fmaxf(oz, 0.f));
        o.w = f2bf(fmaxf(ow, 0.f));
        *reinterpret_cast<ushort4*>(&h[(size_t)n * 128 + c0 + j]) = o;
    } else {
        float4 o;
        o.x = fmaxf(ox, 0.f);
        o.y = fmaxf(oy, 0.f);
        o.z = fmaxf(oz, 0.f);
        o.w = fmaxf(ow, 0.f);
        *reinterpret_cast<float4*>(&outp[(size_t)n * 64 + c0 + j]) = o;
    }
}

static inline int cdiv(int a, int b) { return (a + b - 1) / b; }

template <int CH>
static void run_pipeline(const float* x, const float* W1, const float* b1,
                         const float* W2, const float* b2, const int* edges,
                         float* out, void* d_ws, int N, int E, hipStream_t stream) {
    const int nb = cdiv(N, 1024);
    auto align256 = [](char* p) { return (char*)(((uintptr_t)p + 255) & ~(uintptr_t)255); };
    char* w = (char*)d_ws;
    unsigned* cnt = (unsigned*)w;               // aliased with s
    float* s = (float*)w;                       w = align256(w + (size_t)6 * N * 4);
    __hip_bfloat16* h = (__hip_bfloat16*)w;     w = align256(w + (size_t)N * 128 * 2);
    __hip_bfloat16* T = (__hip_bfloat16*)w;     w = align256(w + (size_t)3 * N * CH * 2);
    int* off = (int*)w;                         w = align256(w + (size_t)3 * (N + 1) * 4);
    int* csr = (int*)w;
    // cur and bsum are dead before the first GEMM writes T -> alias into T region.
    int* cur = (int*)T;
    unsigned* bsum = (unsigned*)((char*)T + (size_t)3 * N * 4 + 256);

    // ---- graph preprocessing ----
    hipMemsetAsync(cnt, 0, (size_t)6 * N * 4, stream);
    count_kernel<<<cdiv(6 * E, TPB), TPB, 0, stream>>>(edges, cnt, 6 * E, E, N);
    scan_local_kernel<<<3 * nb, 256, 0, stream>>>(cnt, off, bsum, N, nb);
    scan_bsum_kernel<<<1, 128, 0, stream>>>(bsum, off, nb, N, E);
    finalize_off_kernel<<<cdiv(3 * N, TPB), TPB, 0, stream>>>(off, bsum, cur, N, nb);
    fill_kernel<<<cdiv(3 * E, TPB), TPB, 0, stream>>>(edges, cur, csr, E, N);
    scale_inplace_kernel<<<cdiv(6 * N, TPB), TPB, 0, stream>>>(cnt, 6 * N);

    const int mgrid = cdiv(N, 64);
    const int ggrid = cdiv(N * (CH / 4), TPB);

    // ---- layer 1: 128 -> 128 ----
    for (int c0 = 0; c0 < 128; c0 += CH) {
        mfma_gemm3_kernel<CH, float><<<mgrid, 256, 0, stream>>>(x, W1, 128, c0, T, N);
        gather3_kernel<CH, 0><<<ggrid, TPB, 0, stream>>>(off, csr, T, s, b1, 128, c0,
                                                         nullptr, h, N, E);
    }
    // ---- layer 2: 128 -> 64 ----
    for (int c0 = 0; c0 < 64; c0 += CH) {
        mfma_gemm3_kernel<CH, __hip_bfloat16><<<mgrid, 256, 0, stream>>>(h, W2, 64, c0, T, N);
        gather3_kernel<CH, 1><<<ggrid, TPB, 0, stream>>>(off, csr, T, s, b2, 64, c0,
                                                         out, nullptr, N, E);
    }
}

extern "C" void kernel_launch(void* const* d_in, const int* in_sizes, int n_in,
                              void* d_out, int out_size, void* d_ws, size_t ws_size,
                              hipStream_t stream) {
    const float* x  = (const float*)d_in[0];   // [N,128]
    const float* W1 = (const float*)d_in[1];   // [3,128,128]
    const float* b1 = (const float*)d_in[2];   // [3,128]
    const float* W2 = (const float*)d_in[3];   // [3,128,64]
    const float* b2 = (const float*)d_in[4];   // [3,64]
    const int*   edges = (const int*)d_in[5];  // [3,2,E] int32
    float* out = (float*)d_out;                // [N,64]

    const int N = in_sizes[0] / 128;
    const int E = in_sizes[5] / 6;

    // CH=64 path needs: 6N*4 + N*128*2 + 3*N*64*2 + 3*(N+1)*4 + 3*E*4 (+pads)
    const size_t need64 = (size_t)6 * N * 4 + (size_t)N * 128 * 2 + (size_t)3 * N * 64 * 2 +
                          (size_t)3 * (N + 1) * 4 + (size_t)3 * E * 4 + 4096;
    if (ws_size >= need64)
        run_pipeline<64>(x, W1, b1, W2, b2, edges, out, d_ws, N, E, stream);
    else
        run_pipeline<32>(x, W1, b1, W2, b2, edges, out, d_ws, N, E, stream);
}

// Round 7
// 461.184 us; speedup vs baseline: 6.4087x; 1.0752x over previous
//
#include <hip/hip_runtime.h>
#include <hip/hip_bf16.h>
#include <stdint.h>

// RGCN on MI355X — round 6 resubmit (round-6 bench hit GPUAcquisitionTimeout;
// kernel never ran). Fully-fused CH=64 path that FITS the proven ws budget
// (45.8MB < 53.6MB proven in round 2), h stored in d_out (bf16), s_out folded
// into GEMM epilogue, gather at 8 lanes x 8 cols w/ 2x unroll.
//
// Liveness: layer1 gather writes h into d_out; layer2 GEMM reads h -> T;
// layer2 gather reads T, overwrites d_out with final f32 [N,64]. No overlap.

constexpr int TPB = 256;

typedef __attribute__((ext_vector_type(8))) short short8;
typedef __attribute__((ext_vector_type(4))) float f32x4;

__device__ __forceinline__ float bf2f(unsigned short u) {
    return __uint_as_float(((unsigned)u) << 16);
}
__device__ __forceinline__ unsigned short f2bf(float f) {
    return __bfloat16_as_ushort(__float2bfloat16(f));
}

// ---------------- graph preprocessing ----------------

__global__ void count_kernel(const int* __restrict__ edges, unsigned* __restrict__ cnt,
                             int total, int E, int N) {
    int i = blockIdx.x * blockDim.x + threadIdx.x;
    if (i >= total) return;
    atomicAdd(&cnt[(size_t)(i / E) * N + edges[i]], 1u);
}

__global__ __launch_bounds__(256) void scan_local_kernel(const unsigned* __restrict__ cnt,
                                                         int* __restrict__ off,
                                                         unsigned* __restrict__ bsum,
                                                         int N, int nb) {
    int r = blockIdx.x / nb, blk = blockIdx.x - r * nb;
    const unsigned* in = cnt + (size_t)(2 * r + 1) * N;  // in-degree slot
    int* o = off + (size_t)r * (N + 1);
    const int t = threadIdx.x, lane = t & 63, wid = t >> 6;
    int base = blk * 1024 + t * 4;
    unsigned v0 = (base + 0 < N) ? in[base + 0] : 0u;
    unsigned v1 = (base + 1 < N) ? in[base + 1] : 0u;
    unsigned v2 = (base + 2 < N) ? in[base + 2] : 0u;
    unsigned v3 = (base + 3 < N) ? in[base + 3] : 0u;
    unsigned p1 = v0, p2 = p1 + v1, p3 = p2 + v2, tt = p3 + v3;
    unsigned x = tt;
#pragma unroll
    for (int d = 1; d < 64; d <<= 1) {
        unsigned tmp = __shfl_up(x, d, 64);
        if (lane >= d) x += tmp;
    }
    __shared__ unsigned ws4[4];
    if (lane == 63) ws4[wid] = x;
    __syncthreads();
    unsigned woff = 0;
#pragma unroll
    for (int w2 = 0; w2 < 4; ++w2)
        if (w2 < wid) woff += ws4[w2];
    unsigned excl = woff + x - tt;
    if (base + 0 < N) o[base + 0] = (int)excl;
    if (base + 1 < N) o[base + 1] = (int)(excl + p1);
    if (base + 2 < N) o[base + 2] = (int)(excl + p2);
    if (base + 3 < N) o[base + 3] = (int)(excl + p3);
    if (t == 255) bsum[r * nb + blk] = woff + x;
}

__global__ __launch_bounds__(128) void scan_bsum_kernel(unsigned* __restrict__ bsum,
                                                        int* __restrict__ off,
                                                        int nb, int N, int E) {
    const int t = threadIdx.x, lane = t & 63, wid = t >> 6;
    __shared__ unsigned wtot[2];
    for (int r = 0; r < 3; ++r) {
        unsigned v = (t < nb) ? bsum[r * nb + t] : 0u;
        unsigned x = v;
#pragma unroll
        for (int d = 1; d < 64; d <<= 1) {
            unsigned tmp = __shfl_up(x, d, 64);
            if (lane >= d) x += tmp;
        }
        if (lane == 63) wtot[wid] = x;
        __syncthreads();
        unsigned add = (wid == 1) ? wtot[0] : 0u;
        if (t < nb) bsum[r * nb + t] = add + x - v;  // exclusive
        if (t == 0) off[(size_t)r * (N + 1) + N] = E;
        __syncthreads();
    }
}

__global__ void finalize_off_kernel(int* __restrict__ off, const unsigned* __restrict__ bsum,
                                    int* __restrict__ cur, int N, int nb) {
    int i = blockIdx.x * blockDim.x + threadIdx.x;
    if (i >= 3 * N) return;
    int r = i / N, n = i - r * N;
    int v = off[(size_t)r * (N + 1) + n] + (int)bsum[r * nb + (n >> 10)];
    off[(size_t)r * (N + 1) + n] = v;
    cur[i] = v;
}

__global__ void fill_kernel(const int* __restrict__ edges, int* __restrict__ cur,
                            int* __restrict__ csr_src, int E, int N) {
    int gid = blockIdx.x * blockDim.x + threadIdx.x;
    if (gid >= 3 * E) return;
    int r = gid / E, e = gid - r * E;
    int d  = edges[(size_t)(2 * r + 1) * E + e];
    int sv = edges[(size_t)(2 * r) * E + e];
    int pos = atomicAdd(&cur[(size_t)r * N + d], 1);
    csr_src[(size_t)r * E + pos] = sv;
}

__global__ void scale_inplace_kernel(unsigned* __restrict__ buf, int total) {
    int i = blockIdx.x * blockDim.x + threadIdx.x;
    if (i >= total) return;
    unsigned c = buf[i];
    ((float*)buf)[i] = rsqrtf((float)(c ? c : 1u));
}

// ---------------- fused 3-relation MFMA GEMM (s_out folded in epilogue) ----------------
// T_r[N,CH](bf16) = s_out_r[n] * (X[N,128] @ W[r][128, c0:c0+CH]).
// Block: 64 rows, 4 waves; wave wv owns rows [16wv,16wv+16), all 3*CH cols.
// W staged in MFMA B-fragment layout LDS (conflict-free ds_read_b128).
// Layouts (m89-verified, validated rounds 4/5): A: row=lane&15, k=(lane>>4)*8+j;
// B: col=lane&15, same k; D: col=lane&15, row=(lane>>4)*4+reg.

template <int CH, typename XT>
__global__ __launch_bounds__(256) void mfma_gemm3_kernel(const XT* __restrict__ X,
                                                         const float* __restrict__ W,
                                                         int WS, int c0,
                                                         const float* __restrict__ s,
                                                         __hip_bfloat16* __restrict__ T, int N) {
    constexpr int CT = CH / 16;   // col-tiles per relation
    constexpr int FR = 4 * CT;    // frags per relation
    __shared__ short bs[3 * FR * 512];
    const int t = threadIdx.x;
    const int lane = t & 63, wv = t >> 6;
    const int m0 = blockIdx.x * 64;

    // stage W chunks of all 3 relations -> fragment-layout LDS
    constexpr int TOT = 3 * 32 * CH;  // (rel, r4, cc): each entry covers 4 W-rows
    for (int linear = t; linear < TOT; linear += 256) {
        int rrel = linear / (32 * CH);
        int rem = linear - rrel * (32 * CH);
        int r4 = rem / CH, cc = rem - r4 * CH;
        int r = r4 << 2;
        const float* wp = W + (size_t)rrel * 128 * WS + (size_t)r * WS + c0 + cc;
        unsigned u0 = f2bf(wp[0]);
        unsigned u1 = f2bf(wp[WS]);
        unsigned u2 = f2bf(wp[2 * WS]);
        unsigned u3 = f2bf(wp[3 * WS]);
        int kk = r4 >> 3, jg = (r4 >> 1) & 3, j0 = (r4 & 1) * 4;
        int l = jg * 16 + (cc & 15), c = cc >> 4;
        int slot = ((rrel * FR + kk * CT + c) << 9) + l * 8 + j0;
        *reinterpret_cast<uint2*>(&bs[slot]) = make_uint2(u0 | (u1 << 16), u2 | (u3 << 16));
    }

    // A fragments straight from global (f32->bf16 inline for layer 1)
    const int row = m0 + wv * 16 + (lane & 15);
    const bool ok = row < N;
    short8 a[4];
    if constexpr (sizeof(XT) == 4) {
        const float* xr = (const float*)X + (size_t)row * 128 + ((lane >> 4) << 3);
#pragma unroll
        for (int kk = 0; kk < 4; ++kk) {
            short8 av = {};
            if (ok) {
                float4 f0 = *reinterpret_cast<const float4*>(xr + kk * 32);
                float4 f1 = *reinterpret_cast<const float4*>(xr + kk * 32 + 4);
                av[0] = (short)f2bf(f0.x); av[1] = (short)f2bf(f0.y);
                av[2] = (short)f2bf(f0.z); av[3] = (short)f2bf(f0.w);
                av[4] = (short)f2bf(f1.x); av[5] = (short)f2bf(f1.y);
                av[6] = (short)f2bf(f1.z); av[7] = (short)f2bf(f1.w);
            }
            a[kk] = av;
        }
    } else {
        const short* xr = (const short*)X + (size_t)row * 128 + ((lane >> 4) << 3);
#pragma unroll
        for (int kk = 0; kk < 4; ++kk) {
            short8 av = {};
            if (ok) av = *reinterpret_cast<const short8*>(xr + kk * 32);
            a[kk] = av;
        }
    }

    __syncthreads();

    f32x4 acc4[3 * CT];
#pragma unroll
    for (int f = 0; f < 3 * CT; ++f) acc4[f] = {0.f, 0.f, 0.f, 0.f};
#pragma unroll
    for (int rrel = 0; rrel < 3; ++rrel) {
#pragma unroll
        for (int c = 0; c < CT; ++c) {
#pragma unroll
            for (int kk = 0; kk < 4; ++kk) {
                short8 b = *reinterpret_cast<const short8*>(
                    &bs[((rrel * FR + kk * CT + c) << 9) + lane * 8]);
                acc4[rrel * CT + c] =
                    __builtin_amdgcn_mfma_f32_16x16x32_bf16(a[kk], b, acc4[rrel * CT + c], 0, 0, 0);
            }
        }
    }

    // epilogue: scale rows by s_out_r and store bf16
#pragma unroll
    for (int rrel = 0; rrel < 3; ++rrel) {
        const float* so = s + (size_t)(2 * rrel) * N;
        __hip_bfloat16* Tr = T + (size_t)rrel * N * CH;
#pragma unroll
        for (int q = 0; q < 4; ++q) {
            int grow = m0 + wv * 16 + ((lane >> 4) << 2) + q;
            if (grow < N) {
                float sc = so[grow];
#pragma unroll
                for (int c = 0; c < CT; ++c) {
                    int gcol = c * 16 + (lane & 15);
                    Tr[(size_t)grow * CH + gcol] = __float2bfloat16(acc4[rrel * CT + c][q] * sc);
                }
            }
        }
    }
}

// ---------------- fused 3-relation gather ----------------
// 8 lanes per node, 8 cols per lane. Per edge: csr[e] + one short8 T-row read
// (s_out already folded into T). o = bias_sum + sum_r s_in_r[n]*sum_e T'_r[src].
// PHASE 0: h[n,c0+j..] = bf16(relu(o))   PHASE 1: out[n,j..] = relu(o)

template <int CH, int PHASE>
__global__ __launch_bounds__(256) void gather3_kernel(const int* __restrict__ off,
                                                      const int* __restrict__ csr,
                                                      const __hip_bfloat16* __restrict__ T,
                                                      const float* __restrict__ s,
                                                      const float* __restrict__ b, int FT, int c0,
                                                      float* __restrict__ outp,
                                                      __hip_bfloat16* __restrict__ h,
                                                      int N, int E) {
    int gid = blockIdx.x * blockDim.x + threadIdx.x;
    int n = gid >> 3;
    if (n >= N) return;
    int j = (gid & 7) << 3;   // 8 cols per lane
    int bj = c0 + j;
    float o[8];
#pragma unroll
    for (int k = 0; k < 8; ++k)
        o[k] = b[bj + k] + b[FT + bj + k] + b[2 * FT + bj + k];
#pragma unroll
    for (int r = 0; r < 3; ++r) {
        const int* offr = off + (size_t)r * (N + 1);
        const int* csrr = csr + (size_t)r * E;
        const __hip_bfloat16* Tr = T + (size_t)r * N * CH;
        int e0 = offr[n], e1 = offr[n + 1];
        float acc[8];
#pragma unroll
        for (int k = 0; k < 8; ++k) acc[k] = 0.f;
        int e = e0;
        for (; e + 2 <= e1; e += 2) {  // 2x unroll: two independent csr->T chains
            int p0 = csrr[e], p1 = csrr[e + 1];
            short8 r0 = *reinterpret_cast<const short8*>(&Tr[(size_t)p0 * CH + j]);
            short8 r1 = *reinterpret_cast<const short8*>(&Tr[(size_t)p1 * CH + j]);
#pragma unroll
            for (int k = 0; k < 8; ++k)
                acc[k] += bf2f((unsigned short)r0[k]) + bf2f((unsigned short)r1[k]);
        }
        if (e < e1) {
            int p0 = csrr[e];
            short8 r0 = *reinterpret_cast<const short8*>(&Tr[(size_t)p0 * CH + j]);
#pragma unroll
            for (int k = 0; k < 8; ++k) acc[k] += bf2f((unsigned short)r0[k]);
        }
        float si = s[(size_t)(2 * r + 1) * N + n];
#pragma unroll
        for (int k = 0; k < 8; ++k) o[k] += si * acc[k];
    }
    if constexpr (PHASE == 0) {
        short8 pk;
#pragma unroll
        for (int k = 0; k < 8; ++k) pk[k] = (short)f2bf(fmaxf(o[k], 0.f));
        *reinterpret_cast<short8*>(&h[(size_t)n * 128 + c0 + j]) = pk;
    } else {
        float4 v0, v1;
        v0.x = fmaxf(o[0], 0.f); v0.y = fmaxf(o[1], 0.f);
        v0.z = fmaxf(o[2], 0.f); v0.w = fmaxf(o[3], 0.f);
        v1.x = fmaxf(o[4], 0.f); v1.y = fmaxf(o[5], 0.f);
        v1.z = fmaxf(o[6], 0.f); v1.w = fmaxf(o[7], 0.f);
        float* p = &outp[(size_t)n * 64 + j];
        *reinterpret_cast<float4*>(p) = v0;
        *reinterpret_cast<float4*>(p + 4) = v1;
    }
}

static inline int cdiv(int a, int b) { return (a + b - 1) / b; }

extern "C" void kernel_launch(void* const* d_in, const int* in_sizes, int n_in,
                              void* d_out, int out_size, void* d_ws, size_t ws_size,
                              hipStream_t stream) {
    const float* x  = (const float*)d_in[0];   // [N,128]
    const float* W1 = (const float*)d_in[1];   // [3,128,128]
    const float* b1 = (const float*)d_in[2];   // [3,128]
    const float* W2 = (const float*)d_in[3];   // [3,128,64]
    const float* b2 = (const float*)d_in[4];   // [3,64]
    const int*   edges = (const int*)d_in[5];  // [3,2,E] int32
    float* out = (float*)d_out;                // [N,64]

    const int N = in_sizes[0] / 128;
    const int E = in_sizes[5] / 6;
    const int nb = cdiv(N, 1024);
    constexpr int CH = 64;

    // ws layout: s(2.4MB) | T(38.4MB) | off(1.2MB) | csr(3.6MB) ~= 45.8MB
    // (proven safe: round-2 demonstrated ws_size >= 53.6MB). h lives in d_out.
    auto align256 = [](char* p) { return (char*)(((uintptr_t)p + 255) & ~(uintptr_t)255); };
    char* w = (char*)d_ws;
    unsigned* cnt = (unsigned*)w;               // aliased with s
    float* s = (float*)w;                       w = align256(w + (size_t)6 * N * 4);
    __hip_bfloat16* T = (__hip_bfloat16*)w;     w = align256(w + (size_t)3 * N * CH * 2);
    int* off = (int*)w;                         w = align256(w + (size_t)3 * (N + 1) * 4);
    int* csr = (int*)w;
    // cur and bsum are dead before the first GEMM writes T -> alias into T region.
    int* cur = (int*)T;
    unsigned* bsum = (unsigned*)((char*)T + (size_t)3 * N * 4 + 256);
    __hip_bfloat16* h = (__hip_bfloat16*)d_out; // [N,128] bf16 == 25.6MB == d_out size

    // ---- graph preprocessing ----
    hipMemsetAsync(cnt, 0, (size_t)6 * N * 4, stream);
    count_kernel<<<cdiv(6 * E, TPB), TPB, 0, stream>>>(edges, cnt, 6 * E, E, N);
    scan_local_kernel<<<3 * nb, 256, 0, stream>>>(cnt, off, bsum, N, nb);
    scan_bsum_kernel<<<1, 128, 0, stream>>>(bsum, off, nb, N, E);
    finalize_off_kernel<<<cdiv(3 * N, TPB), TPB, 0, stream>>>(off, bsum, cur, N, nb);
    fill_kernel<<<cdiv(3 * E, TPB), TPB, 0, stream>>>(edges, cur, csr, E, N);
    scale_inplace_kernel<<<cdiv(6 * N, TPB), TPB, 0, stream>>>(cnt, 6 * N);

    const int mgrid = cdiv(N, 64);
    const int ggrid = cdiv(N * 8, TPB);

    // ---- layer 1: 128 -> 128 (two 64-col chunks); h -> d_out (bf16) ----
    for (int c0 = 0; c0 < 128; c0 += CH) {
        mfma_gemm3_kernel<CH, float><<<mgrid, 256, 0, stream>>>(x, W1, 128, c0, s, T, N);
        gather3_kernel<CH, 0><<<ggrid, TPB, 0, stream>>>(off, csr, T, s, b1, 128, c0,
                                                         nullptr, h, N, E);
    }
    // ---- layer 2: 128 -> 64 (one chunk); overwrites d_out with final f32 ----
    mfma_gemm3_kernel<CH, __hip_bfloat16><<<mgrid, 256, 0, stream>>>(h, W2, 64, 0, s, T, N);
    gather3_kernel<CH, 1><<<ggrid, TPB, 0, stream>>>(off, csr, T, s, b2, 64, 0,
                                                     out, nullptr, N, E);
}

// Round 8
// 440.019 us; speedup vs baseline: 6.7169x; 1.0481x over previous
//
#include <hip/hip_runtime.h>
#include <hip/hip_bf16.h>
#include <stdint.h>

// RGCN on MI355X — round 8: unified tagged CSR (one dst-sorted edge list for
// all 3 relations, value = (r<<17)|src) + unroll-4 gather for 4 in-flight
// csr->T-row chains. Gathers were latency-bound (~2TB/s effective on
// L3-resident T) with per-relation Poisson(3) loops at 46% lane utilization.
//
// Unchanged: count (atomic-bound 70us floor), MFMA GEMM w/ s_out epilogue,
// h in d_out (bf16), ws ~44.9MB < 53.6MB proven budget.

constexpr int TPB = 256;

typedef __attribute__((ext_vector_type(8))) short short8;
typedef __attribute__((ext_vector_type(4))) float f32x4;

__device__ __forceinline__ float bf2f(unsigned short u) {
    return __uint_as_float(((unsigned)u) << 16);
}
__device__ __forceinline__ unsigned short f2bf(float f) {
    return __bfloat16_as_ushort(__float2bfloat16(f));
}

// ---------------- graph preprocessing ----------------

// cnt layout [6N]: slot 2r = out-deg(rel r), slot 2r+1 = in-deg(rel r).
__global__ void count_kernel(const int* __restrict__ edges, unsigned* __restrict__ cnt,
                             int total, int E, int N) {
    int i = blockIdx.x * blockDim.x + threadIdx.x;
    if (i >= total) return;
    atomicAdd(&cnt[(size_t)(i / E) * N + edges[i]], 1u);
}

// Exclusive scan over per-node TOTAL in-degree (sum of the 3 relations).
__global__ __launch_bounds__(256) void scan_local_kernel(const unsigned* __restrict__ cnt,
                                                         int* __restrict__ off,
                                                         unsigned* __restrict__ bsum,
                                                         int N) {
    int blk = blockIdx.x;
    const int t = threadIdx.x, lane = t & 63, wid = t >> 6;
    int base = blk * 1024 + t * 4;
    unsigned v[4];
#pragma unroll
    for (int k = 0; k < 4; ++k) {
        int i = base + k;
        v[k] = (i < N) ? (cnt[(size_t)N + i] + cnt[(size_t)3 * N + i] + cnt[(size_t)5 * N + i])
                       : 0u;
    }
    unsigned p1 = v[0], p2 = p1 + v[1], p3 = p2 + v[2], tt = p3 + v[3];
    unsigned x = tt;
#pragma unroll
    for (int d = 1; d < 64; d <<= 1) {
        unsigned tmp = __shfl_up(x, d, 64);
        if (lane >= d) x += tmp;
    }
    __shared__ unsigned ws4[4];
    if (lane == 63) ws4[wid] = x;
    __syncthreads();
    unsigned woff = 0;
#pragma unroll
    for (int w2 = 0; w2 < 4; ++w2)
        if (w2 < wid) woff += ws4[w2];
    unsigned excl = woff + x - tt;
    if (base + 0 < N) off[base + 0] = (int)excl;
    if (base + 1 < N) off[base + 1] = (int)(excl + p1);
    if (base + 2 < N) off[base + 2] = (int)(excl + p2);
    if (base + 3 < N) off[base + 3] = (int)(excl + p3);
    if (t == 255) bsum[blk] = woff + x;
}

// One block: exclusive scan of per-tile sums (nb <= 128).
__global__ __launch_bounds__(128) void scan_bsum_kernel(unsigned* __restrict__ bsum,
                                                        int* __restrict__ off,
                                                        int nb, int N, int TE) {
    const int t = threadIdx.x, lane = t & 63, wid = t >> 6;
    __shared__ unsigned wtot[2];
    unsigned v = (t < nb) ? bsum[t] : 0u;
    unsigned x = v;
#pragma unroll
    for (int d = 1; d < 64; d <<= 1) {
        unsigned tmp = __shfl_up(x, d, 64);
        if (lane >= d) x += tmp;
    }
    if (lane == 63) wtot[wid] = x;
    __syncthreads();
    unsigned add = (wid == 1) ? wtot[0] : 0u;
    if (t < nb) bsum[t] = add + x - v;  // exclusive
    if (t == 0) off[N] = TE;
}

__global__ void finalize_off_kernel(int* __restrict__ off, const unsigned* __restrict__ bsum,
                                    int* __restrict__ cur, int N) {
    int i = blockIdx.x * blockDim.x + threadIdx.x;
    if (i >= N) return;
    int v = off[i] + (int)bsum[i >> 10];
    off[i] = v;
    cur[i] = v;
}

// csr[pos] = (r<<17) | src   (N=100k < 2^17; r in 0..2)
__global__ void fill_kernel(const int* __restrict__ edges, int* __restrict__ cur,
                            int* __restrict__ csr, int E, int N) {
    int gid = blockIdx.x * blockDim.x + threadIdx.x;
    if (gid >= 3 * E) return;
    int r = gid / E, e = gid - r * E;
    int d  = edges[(size_t)(2 * r + 1) * E + e];
    int sv = edges[(size_t)(2 * r) * E + e];
    int pos = atomicAdd(&cur[d], 1);
    csr[pos] = (r << 17) | sv;
}

__global__ void scale_inplace_kernel(unsigned* __restrict__ buf, int total) {
    int i = blockIdx.x * blockDim.x + threadIdx.x;
    if (i >= total) return;
    unsigned c = buf[i];
    ((float*)buf)[i] = rsqrtf((float)(c ? c : 1u));
}

// ---------------- fused 3-relation MFMA GEMM (s_out folded in epilogue) ----------------
// T_r[N,CH](bf16) = s_out_r[n] * (X[N,128] @ W[r][128, c0:c0+CH]).
// Layouts (m89-verified, validated rounds 4/5/7): A: row=lane&15, k=(lane>>4)*8+j;
// B: col=lane&15, same k; D: col=lane&15, row=(lane>>4)*4+reg.

template <int CH, typename XT>
__global__ __launch_bounds__(256) void mfma_gemm3_kernel(const XT* __restrict__ X,
                                                         const float* __restrict__ W,
                                                         int WS, int c0,
                                                         const float* __restrict__ s,
                                                         __hip_bfloat16* __restrict__ T, int N) {
    constexpr int CT = CH / 16;   // col-tiles per relation
    constexpr int FR = 4 * CT;    // frags per relation
    __shared__ short bs[3 * FR * 512];
    const int t = threadIdx.x;
    const int lane = t & 63, wv = t >> 6;
    const int m0 = blockIdx.x * 64;

    constexpr int TOT = 3 * 32 * CH;  // (rel, r4, cc): each entry covers 4 W-rows
    for (int linear = t; linear < TOT; linear += 256) {
        int rrel = linear / (32 * CH);
        int rem = linear - rrel * (32 * CH);
        int r4 = rem / CH, cc = rem - r4 * CH;
        int r = r4 << 2;
        const float* wp = W + (size_t)rrel * 128 * WS + (size_t)r * WS + c0 + cc;
        unsigned u0 = f2bf(wp[0]);
        unsigned u1 = f2bf(wp[WS]);
        unsigned u2 = f2bf(wp[2 * WS]);
        unsigned u3 = f2bf(wp[3 * WS]);
        int kk = r4 >> 3, jg = (r4 >> 1) & 3, j0 = (r4 & 1) * 4;
        int l = jg * 16 + (cc & 15), c = cc >> 4;
        int slot = ((rrel * FR + kk * CT + c) << 9) + l * 8 + j0;
        *reinterpret_cast<uint2*>(&bs[slot]) = make_uint2(u0 | (u1 << 16), u2 | (u3 << 16));
    }

    const int row = m0 + wv * 16 + (lane & 15);
    const bool ok = row < N;
    short8 a[4];
    if constexpr (sizeof(XT) == 4) {
        const float* xr = (const float*)X + (size_t)row * 128 + ((lane >> 4) << 3);
#pragma unroll
        for (int kk = 0; kk < 4; ++kk) {
            short8 av = {};
            if (ok) {
                float4 f0 = *reinterpret_cast<const float4*>(xr + kk * 32);
                float4 f1 = *reinterpret_cast<const float4*>(xr + kk * 32 + 4);
                av[0] = (short)f2bf(f0.x); av[1] = (short)f2bf(f0.y);
                av[2] = (short)f2bf(f0.z); av[3] = (short)f2bf(f0.w);
                av[4] = (short)f2bf(f1.x); av[5] = (short)f2bf(f1.y);
                av[6] = (short)f2bf(f1.z); av[7] = (short)f2bf(f1.w);
            }
            a[kk] = av;
        }
    } else {
        const short* xr = (const short*)X + (size_t)row * 128 + ((lane >> 4) << 3);
#pragma unroll
        for (int kk = 0; kk < 4; ++kk) {
            short8 av = {};
            if (ok) av = *reinterpret_cast<const short8*>(xr + kk * 32);
            a[kk] = av;
        }
    }

    __syncthreads();

    f32x4 acc4[3 * CT];
#pragma unroll
    for (int f = 0; f < 3 * CT; ++f) acc4[f] = {0.f, 0.f, 0.f, 0.f};
#pragma unroll
    for (int rrel = 0; rrel < 3; ++rrel) {
#pragma unroll
        for (int c = 0; c < CT; ++c) {
#pragma unroll
            for (int kk = 0; kk < 4; ++kk) {
                short8 b = *reinterpret_cast<const short8*>(
                    &bs[((rrel * FR + kk * CT + c) << 9) + lane * 8]);
                acc4[rrel * CT + c] =
                    __builtin_amdgcn_mfma_f32_16x16x32_bf16(a[kk], b, acc4[rrel * CT + c], 0, 0, 0);
            }
        }
    }

#pragma unroll
    for (int rrel = 0; rrel < 3; ++rrel) {
        const float* so = s + (size_t)(2 * rrel) * N;
        __hip_bfloat16* Tr = T + (size_t)rrel * N * CH;
#pragma unroll
        for (int q = 0; q < 4; ++q) {
            int grow = m0 + wv * 16 + ((lane >> 4) << 2) + q;
            if (grow < N) {
                float sc = so[grow];
#pragma unroll
                for (int c = 0; c < CT; ++c) {
                    int gcol = c * 16 + (lane & 15);
                    Tr[(size_t)grow * CH + gcol] = __float2bfloat16(acc4[rrel * CT + c][q] * sc);
                }
            }
        }
    }
}

// ---------------- unified-CSR gather ----------------
// 8 lanes per node, 8 cols per lane. Single edge loop over all 3 relations,
// unroll 4 (4 independent csr->T-row chains in flight). Per edge: decode
// (r,src) from tag, w = s_in_r[n], o[k] += w * T[(r*N+src), j+k].
// PHASE 0: h[n,c0+j..] = bf16(relu(o))   PHASE 1: out[n,j..] = relu(o)

template <int CH, int PHASE>
__global__ __launch_bounds__(256) void gather_u_kernel(const int* __restrict__ off,
                                                       const int* __restrict__ csr,
                                                       const __hip_bfloat16* __restrict__ T,
                                                       const float* __restrict__ s,
                                                       const float* __restrict__ b, int FT, int c0,
                                                       float* __restrict__ outp,
                                                       __hip_bfloat16* __restrict__ h,
                                                       int N) {
    int gid = blockIdx.x * blockDim.x + threadIdx.x;
    int n = gid >> 3;
    if (n >= N) return;
    int j = (gid & 7) << 3;   // 8 cols per lane
    int bj = c0 + j;
    float o[8];
#pragma unroll
    for (int k = 0; k < 8; ++k)
        o[k] = b[bj + k] + b[FT + bj + k] + b[2 * FT + bj + k];

    const float si0 = s[(size_t)1 * N + n];
    const float si1 = s[(size_t)3 * N + n];
    const float si2 = s[(size_t)5 * N + n];

    int e0 = off[n], e1 = off[n + 1];
    int e = e0;
    for (; e + 4 <= e1; e += 4) {
        int v0 = csr[e], v1 = csr[e + 1], v2 = csr[e + 2], v3 = csr[e + 3];
        int r0 = v0 >> 17, r1 = v1 >> 17, r2 = v2 >> 17, r3 = v3 >> 17;
        const short8* p0 = reinterpret_cast<const short8*>(
            &T[((size_t)r0 * N + (v0 & 0x1FFFF)) * CH + j]);
        const short8* p1 = reinterpret_cast<const short8*>(
            &T[((size_t)r1 * N + (v1 & 0x1FFFF)) * CH + j]);
        const short8* p2 = reinterpret_cast<const short8*>(
            &T[((size_t)r2 * N + (v2 & 0x1FFFF)) * CH + j]);
        const short8* p3 = reinterpret_cast<const short8*>(
            &T[((size_t)r3 * N + (v3 & 0x1FFFF)) * CH + j]);
        short8 t0 = *p0, t1 = *p1, t2 = *p2, t3 = *p3;
        float w0 = r0 == 0 ? si0 : (r0 == 1 ? si1 : si2);
        float w1 = r1 == 0 ? si0 : (r1 == 1 ? si1 : si2);
        float w2 = r2 == 0 ? si0 : (r2 == 1 ? si1 : si2);
        float w3 = r3 == 0 ? si0 : (r3 == 1 ? si1 : si2);
#pragma unroll
        for (int k = 0; k < 8; ++k) {
            o[k] += w0 * bf2f((unsigned short)t0[k]);
            o[k] += w1 * bf2f((unsigned short)t1[k]);
            o[k] += w2 * bf2f((unsigned short)t2[k]);
            o[k] += w3 * bf2f((unsigned short)t3[k]);
        }
    }
    for (; e < e1; ++e) {
        int v0 = csr[e];
        int r0 = v0 >> 17;
        short8 t0 = *reinterpret_cast<const short8*>(
            &T[((size_t)r0 * N + (v0 & 0x1FFFF)) * CH + j]);
        float w0 = r0 == 0 ? si0 : (r0 == 1 ? si1 : si2);
#pragma unroll
        for (int k = 0; k < 8; ++k) o[k] += w0 * bf2f((unsigned short)t0[k]);
    }

    if constexpr (PHASE == 0) {
        short8 pk;
#pragma unroll
        for (int k = 0; k < 8; ++k) pk[k] = (short)f2bf(fmaxf(o[k], 0.f));
        *reinterpret_cast<short8*>(&h[(size_t)n * 128 + c0 + j]) = pk;
    } else {
        float4 v0, v1;
        v0.x = fmaxf(o[0], 0.f); v0.y = fmaxf(o[1], 0.f);
        v0.z = fmaxf(o[2], 0.f); v0.w = fmaxf(o[3], 0.f);
        v1.x = fmaxf(o[4], 0.f); v1.y = fmaxf(o[5], 0.f);
        v1.z = fmaxf(o[6], 0.f); v1.w = fmaxf(o[7], 0.f);
        float* p = &outp[(size_t)n * 64 + j];
        *reinterpret_cast<float4*>(p) = v0;
        *reinterpret_cast<float4*>(p + 4) = v1;
    }
}

static inline int cdiv(int a, int b) { return (a + b - 1) / b; }

extern "C" void kernel_launch(void* const* d_in, const int* in_sizes, int n_in,
                              void* d_out, int out_size, void* d_ws, size_t ws_size,
                              hipStream_t stream) {
    const float* x  = (const float*)d_in[0];   // [N,128]
    const float* W1 = (const float*)d_in[1];   // [3,128,128]
    const float* b1 = (const float*)d_in[2];   // [3,128]
    const float* W2 = (const float*)d_in[3];   // [3,128,64]
    const float* b2 = (const float*)d_in[4];   // [3,64]
    const int*   edges = (const int*)d_in[5];  // [3,2,E] int32
    float* out = (float*)d_out;                // [N,64]

    const int N = in_sizes[0] / 128;
    const int E = in_sizes[5] / 6;
    const int nb = cdiv(N, 1024);
    constexpr int CH = 64;

    // ws layout: s(2.4MB) | T(38.4MB) | off(0.4MB) | csr(3.6MB) ~= 44.9MB
    // (proven safe: ws_size >= 53.6MB from round 2). h lives in d_out.
    auto align256 = [](char* p) { return (char*)(((uintptr_t)p + 255) & ~(uintptr_t)255); };
    char* w = (char*)d_ws;
    unsigned* cnt = (unsigned*)w;               // aliased with s
    float* s = (float*)w;                       w = align256(w + (size_t)6 * N * 4);
    __hip_bfloat16* T = (__hip_bfloat16*)w;     w = align256(w + (size_t)3 * N * CH * 2);
    int* off = (int*)w;                         w = align256(w + (size_t)(N + 1) * 4);
    int* csr = (int*)w;
    // cur and bsum are dead before the first GEMM writes T -> alias into T region.
    int* cur = (int*)T;
    unsigned* bsum = (unsigned*)((char*)T + (size_t)N * 4 + 256);
    __hip_bfloat16* h = (__hip_bfloat16*)d_out; // [N,128] bf16 == 25.6MB == d_out size

    // ---- graph preprocessing ----
    hipMemsetAsync(cnt, 0, (size_t)6 * N * 4, stream);
    count_kernel<<<cdiv(6 * E, TPB), TPB, 0, stream>>>(edges, cnt, 6 * E, E, N);
    scan_local_kernel<<<nb, 256, 0, stream>>>(cnt, off, bsum, N);
    scan_bsum_kernel<<<1, 128, 0, stream>>>(bsum, off, nb, N, 3 * E);
    finalize_off_kernel<<<cdiv(N, TPB), TPB, 0, stream>>>(off, bsum, cur, N);
    fill_kernel<<<cdiv(3 * E, TPB), TPB, 0, stream>>>(edges, cur, csr, E, N);
    scale_inplace_kernel<<<cdiv(6 * N, TPB), TPB, 0, stream>>>(cnt, 6 * N);

    const int mgrid = cdiv(N, 64);
    const int ggrid = cdiv(N * 8, TPB);

    // ---- layer 1: 128 -> 128 (two 64-col chunks); h -> d_out (bf16) ----
    for (int c0 = 0; c0 < 128; c0 += CH) {
        mfma_gemm3_kernel<CH, float><<<mgrid, 256, 0, stream>>>(x, W1, 128, c0, s, T, N);
        gather_u_kernel<CH, 0><<<ggrid, TPB, 0, stream>>>(off, csr, T, s, b1, 128, c0,
                                                          nullptr, h, N);
    }
    // ---- layer 2: 128 -> 64 (one chunk); overwrites d_out with final f32 ----
    mfma_gemm3_kernel<CH, __hip_bfloat16><<<mgrid, 256, 0, stream>>>(h, W2, 64, 0, s, T, N);
    gather_u_kernel<CH, 1><<<ggrid, TPB, 0, stream>>>(off, csr, T, s, b2, 64, 0,
                                                      out, nullptr, N);
}